// Round 1
// baseline (612.706 us; speedup 1.0000x reference)
//
#include <hip/hip_runtime.h>
#include <math.h>

#define NROWS 1048576
#define C 64

constexpr float EPS = 1e-5f;
constexpr float ACOSH_EPS = 1e-7f;

// ws layout (floats): [0:64] col_sums, [64:128] mu, [128] d2sum

__global__ __launch_bounds__(256) void colsum_kernel(
    const float* __restrict__ x, float* __restrict__ ws) {
    const int tid = threadIdx.x;
    const int g = tid & 15;  // column group: columns 4g..4g+3
    const int gid = (blockIdx.x * blockDim.x + tid) >> 4;
    const int gstride = (gridDim.x * blockDim.x) >> 4;
    float4 acc = {0.f, 0.f, 0.f, 0.f};
    for (int r = gid; r < NROWS; r += gstride) {
        const float4 v = *(const float4*)(x + (size_t)r * C + g * 4);
        acc.x += v.x; acc.y += v.y; acc.z += v.z; acc.w += v.w;
    }
    // lanes l, l^16, l^32, l^48 share the same column group
    #pragma unroll
    for (int m = 16; m <= 32; m <<= 1) {
        acc.x += __shfl_xor(acc.x, m, 64);
        acc.y += __shfl_xor(acc.y, m, 64);
        acc.z += __shfl_xor(acc.z, m, 64);
        acc.w += __shfl_xor(acc.w, m, 64);
    }
    __shared__ float lsum[4][64];
    const int wave = tid >> 6, lane = tid & 63;
    if (lane < 16) {
        lsum[wave][lane * 4 + 0] = acc.x;
        lsum[wave][lane * 4 + 1] = acc.y;
        lsum[wave][lane * 4 + 2] = acc.z;
        lsum[wave][lane * 4 + 3] = acc.w;
    }
    __syncthreads();
    if (tid < 64) {
        float s = lsum[0][tid] + lsum[1][tid] + lsum[2][tid] + lsum[3][tid];
        atomicAdd(&ws[tid], s);
    }
}

__global__ void mu_kernel(float* __restrict__ ws) {
    const int j = threadIdx.x;  // 64 threads
    const float s = ws[j] * (1.0f / (float)NROWS);
    float p = s * s;
    if (j == 0) p = -p;
    #pragma unroll
    for (int m = 1; m < 64; m <<= 1) p += __shfl_xor(p, m, 64);
    // p = linner(s,s); -linner = -p
    const float sn = sqrtf(fmaxf(-p, 1e-9f));
    ws[64 + j] = s / sn;
}

__global__ __launch_bounds__(256) void var_kernel(
    const float* __restrict__ x, float* __restrict__ ws) {
    const int tid = threadIdx.x;
    const int g = tid & 15;
    const float4 muv = *(const float4*)(ws + 64 + g * 4);
    const float sgn = (g == 0) ? -1.0f : 1.0f;
    const int gid = (blockIdx.x * blockDim.x + tid) >> 4;
    const int gstride = (gridDim.x * blockDim.x) >> 4;
    float dacc = 0.f;
    for (int r = gid; r < NROWS; r += gstride) {
        const float4 v = *(const float4*)(x + (size_t)r * C + g * 4);
        float p = sgn * v.x * muv.x + v.y * muv.y + v.z * muv.z + v.w * muv.w;
        #pragma unroll
        for (int m = 1; m < 16; m <<= 1) p += __shfl_xor(p, m, 16);
        const float alpha = fmaxf(-p, 1.0f + ACOSH_EPS);
        const float t = alpha * alpha - 1.0f;
        const float d = logf(alpha + sqrtf(t));
        if (g == 0) dacc += d * d;  // count each row once
    }
    #pragma unroll
    for (int m = 1; m < 64; m <<= 1) dacc += __shfl_xor(dacc, m, 64);
    __shared__ float wsum[4];
    const int wave = tid >> 6, lane = tid & 63;
    if (lane == 0) wsum[wave] = dacc;
    __syncthreads();
    if (tid == 0) atomicAdd(&ws[128], wsum[0] + wsum[1] + wsum[2] + wsum[3]);
}

__global__ __launch_bounds__(256) void out_kernel(
    const float* __restrict__ x, const float* __restrict__ gamma,
    const float* __restrict__ beta, float* __restrict__ out,
    const float* __restrict__ ws) {
    const int tid = threadIdx.x;
    const int g = tid & 15;
    const float4 muv = *(const float4*)(ws + 64 + g * 4);
    const float4 bev = *(const float4*)(beta + g * 4);
    const float mu0 = ws[64];
    const float beta0 = beta[0];
    const float var = ws[128] * (1.0f / (float)NROWS);
    const float divv = sqrtf(var + EPS);
    const float gscale = gamma[0] / divv;
    const float inv_dmo = 1.0f / (1.0f + mu0);   // 1 - (-mu0)
    const float inv_dob = 1.0f / (1.0f + beta0); // 1 - (-beta0)
    const float sgn = (g == 0) ? -1.0f : 1.0f;
    const float e0 = (g == 0) ? 1.0f : 0.0f;     // o-vector component in slot .x
    const int gid = (blockIdx.x * blockDim.x + tid) >> 4;
    const int gstride = (gridDim.x * blockDim.x) >> 4;
    for (int r = gid; r < NROWS; r += gstride) {
        const float4 xv = *(const float4*)(x + (size_t)r * C + g * 4);
        // alpha = clip(-linner(x, mu), 1+eps)
        float p = sgn * xv.x * muv.x + xv.y * muv.y + xv.z * muv.z + xv.w * muv.w;
        #pragma unroll
        for (int m = 1; m < 16; m <<= 1) p += __shfl_xor(p, m, 16);
        const float alpha = fmaxf(-p, 1.0f + ACOSH_EPS);
        const float t = alpha * alpha - 1.0f;
        const float d = logf(alpha + sqrtf(t));           // arccosh
        const float f = d * rsqrtf(fmaxf(t, ACOSH_EPS));  // d / sqrt(clip(a^2-1))
        float4 v;
        v.x = f * (xv.x - alpha * muv.x);
        v.y = f * (xv.y - alpha * muv.y);
        v.z = f * (xv.z - alpha * muv.z);
        v.w = f * (xv.w - alpha * muv.w);
        // ov = -v[0]; v += ov/denom_mo * (mu + o)
        const float ov = -__shfl(v.x, 0, 16);
        const float c1 = ov * inv_dmo;
        v.x += c1 * (muv.x + e0);
        v.y += c1 * muv.y;
        v.z += c1 * muv.z;
        v.w += c1 * muv.w;
        // v *= gamma/div
        v.x *= gscale; v.y *= gscale; v.z *= gscale; v.w *= gscale;
        // bv = linner(beta, v); v += bv/denom_ob * (o + beta)
        float bv = sgn * bev.x * v.x + bev.y * v.y + bev.z * v.z + bev.w * v.w;
        #pragma unroll
        for (int m = 1; m < 16; m <<= 1) bv += __shfl_xor(bv, m, 16);
        const float c2 = bv * inv_dob;
        v.x += c2 * (bev.x + e0);
        v.y += c2 * bev.y;
        v.z += c2 * bev.z;
        v.w += c2 * bev.w;
        // vn = sqrt(clip(linner(v,v), 1e-9)); out = cosh(vn)*beta + sinh(vn)*v/vn
        float nn = sgn * v.x * v.x + v.y * v.y + v.z * v.z + v.w * v.w;
        #pragma unroll
        for (int m = 1; m < 16; m <<= 1) nn += __shfl_xor(nn, m, 16);
        const float vn = sqrtf(fmaxf(nn, 1e-9f));
        const float e = expf(vn);
        const float ei = 1.0f / e;
        const float ch = 0.5f * (e + ei);
        const float sc = 0.5f * (e - ei) / vn;  // sinh(vn)/vn
        float4 o;
        o.x = ch * bev.x + sc * v.x;
        o.y = ch * bev.y + sc * v.y;
        o.z = ch * bev.z + sc * v.z;
        o.w = ch * bev.w + sc * v.w;
        *(float4*)(out + (size_t)r * C + g * 4) = o;
    }
}

extern "C" void kernel_launch(void* const* d_in, const int* in_sizes, int n_in,
                              void* d_out, int out_size, void* d_ws, size_t ws_size,
                              hipStream_t stream) {
    const float* x = (const float*)d_in[0];
    const float* gamma = (const float*)d_in[1];
    const float* beta = (const float*)d_in[2];
    float* out = (float*)d_out;
    float* ws = (float*)d_ws;

    // zero col_sums [0:64], mu [64:128], d2sum [128]
    hipMemsetAsync(ws, 0, 129 * sizeof(float), stream);

    colsum_kernel<<<4096, 256, 0, stream>>>(x, ws);
    mu_kernel<<<1, 64, 0, stream>>>(ws);
    var_kernel<<<4096, 256, 0, stream>>>(x, ws);
    out_kernel<<<4096, 256, 0, stream>>>(x, gamma, beta, out, ws);
}

// Round 2
// 602.595 us; speedup vs baseline: 1.0168x; 1.0168x over previous
//
#include <hip/hip_runtime.h>
#include <math.h>

#define NROWS 1048576
#define C 64
#define GRID 4096
#define BLOCK 256
#define GPT ((GRID * BLOCK) / 16)   // row-groups covered per chunk = 65536
#define NITER (NROWS / GPT)         // 16 chunks

constexpr float EPS = 1e-5f;
constexpr float ACOSH_EPS = 1e-7f;

// ws layout (floats): [0:64] col_sums, [64:128] mu, [128] d2sum(/16)

// Sum across the 16-lane DPP row via rotate-and-add: 4 VALU ops, no LDS pipe.
// Every lane ends with the full row-of-16 sum.
__device__ __forceinline__ float row16_sum(float x) {
    x += __int_as_float(__builtin_amdgcn_update_dpp(
        0, __float_as_int(x), 0x121, 0xF, 0xF, true));  // row_ror:1
    x += __int_as_float(__builtin_amdgcn_update_dpp(
        0, __float_as_int(x), 0x122, 0xF, 0xF, true));  // row_ror:2
    x += __int_as_float(__builtin_amdgcn_update_dpp(
        0, __float_as_int(x), 0x124, 0xF, 0xF, true));  // row_ror:4
    x += __int_as_float(__builtin_amdgcn_update_dpp(
        0, __float_as_int(x), 0x128, 0xF, 0xF, true));  // row_ror:8
    return x;
}

__global__ __launch_bounds__(BLOCK) void colsum_kernel(
    const float* __restrict__ x, float* __restrict__ ws) {
    const int tid = threadIdx.x;
    const int g = tid & 15;
    const int gid0 = (blockIdx.x * BLOCK + tid) >> 4;
    const float* p = x + (size_t)gid0 * C + g * 4;
    float4 a0 = {0, 0, 0, 0}, a1 = {0, 0, 0, 0}, a2 = {0, 0, 0, 0}, a3 = {0, 0, 0, 0};
    #pragma unroll
    for (int k = 0; k < NITER; k += 4) {
        // 4 independent loads in flight per round
        const float4 v0 = *(const float4*)(p + (size_t)(k + 0) * GPT * C);
        const float4 v1 = *(const float4*)(p + (size_t)(k + 1) * GPT * C);
        const float4 v2 = *(const float4*)(p + (size_t)(k + 2) * GPT * C);
        const float4 v3 = *(const float4*)(p + (size_t)(k + 3) * GPT * C);
        a0.x += v0.x; a0.y += v0.y; a0.z += v0.z; a0.w += v0.w;
        a1.x += v1.x; a1.y += v1.y; a1.z += v1.z; a1.w += v1.w;
        a2.x += v2.x; a2.y += v2.y; a2.z += v2.z; a2.w += v2.w;
        a3.x += v3.x; a3.y += v3.y; a3.z += v3.z; a3.w += v3.w;
    }
    float4 acc;
    acc.x = (a0.x + a1.x) + (a2.x + a3.x);
    acc.y = (a0.y + a1.y) + (a2.y + a3.y);
    acc.z = (a0.z + a1.z) + (a2.z + a3.z);
    acc.w = (a0.w + a1.w) + (a2.w + a3.w);
    // lanes l, l^16, l^32, l^48 hold the same column group
    #pragma unroll
    for (int m = 16; m <= 32; m <<= 1) {
        acc.x += __shfl_xor(acc.x, m, 64);
        acc.y += __shfl_xor(acc.y, m, 64);
        acc.z += __shfl_xor(acc.z, m, 64);
        acc.w += __shfl_xor(acc.w, m, 64);
    }
    __shared__ float lsum[4][64];
    const int wave = tid >> 6, lane = tid & 63;
    if (lane < 16) {
        lsum[wave][lane * 4 + 0] = acc.x;
        lsum[wave][lane * 4 + 1] = acc.y;
        lsum[wave][lane * 4 + 2] = acc.z;
        lsum[wave][lane * 4 + 3] = acc.w;
    }
    __syncthreads();
    if (tid < 64) {
        const float s = lsum[0][tid] + lsum[1][tid] + lsum[2][tid] + lsum[3][tid];
        atomicAdd(&ws[tid], s);
    }
}

__global__ void mu_kernel(float* __restrict__ ws) {
    const int j = threadIdx.x;  // 64 threads
    const float s = ws[j] * (1.0f / (float)NROWS);
    float p = s * s;
    if (j == 0) p = -p;
    #pragma unroll
    for (int m = 1; m < 64; m <<= 1) p += __shfl_xor(p, m, 64);
    const float sn = sqrtf(fmaxf(-p, 1e-9f));
    ws[64 + j] = s / sn;
}

__global__ __launch_bounds__(BLOCK) void var_kernel(
    const float* __restrict__ x, float* __restrict__ ws) {
    const int tid = threadIdx.x;
    const int g = tid & 15;
    const int gid0 = (blockIdx.x * BLOCK + tid) >> 4;
    float4 smu = *(const float4*)(ws + 64 + g * 4);
    if (g == 0) smu.x = -smu.x;  // Lorentz sign folded into the mu fragment
    float dacc = 0.f;
    // descending chunk order: re-reads colsum's freshest L3-resident lines first
    #pragma unroll 8
    for (int k = 0; k < NITER; ++k) {
        const size_t r = (size_t)gid0 + (size_t)(NITER - 1 - k) * GPT;
        const float4 v = *(const float4*)(x + r * C + g * 4);
        float p = fmaf(v.x, smu.x, fmaf(v.y, smu.y, fmaf(v.z, smu.z, v.w * smu.w)));
        p = row16_sum(p);
        const float alpha = fmaxf(-p, 1.0f + ACOSH_EPS);
        const float t = fmaf(alpha, alpha, -1.0f);
        const float d = __logf(alpha + sqrtf(t));
        dacc = fmaf(d, d, dacc);  // every lane counts; scale by 1/16 at the end
    }
    dacc = row16_sum(dacc);
    dacc += __shfl_xor(dacc, 16, 64);
    dacc += __shfl_xor(dacc, 32, 64);
    __shared__ float wsum[4];
    const int wave = tid >> 6, lane = tid & 63;
    if (lane == 0) wsum[wave] = dacc;
    __syncthreads();
    if (tid == 0)
        atomicAdd(&ws[128], (wsum[0] + wsum[1] + wsum[2] + wsum[3]) * (1.0f / 16.0f));
}

__global__ __launch_bounds__(BLOCK) void out_kernel(
    const float* __restrict__ x, const float* __restrict__ gamma,
    const float* __restrict__ beta, float* __restrict__ out,
    const float* __restrict__ ws) {
    const int tid = threadIdx.x;
    const int g = tid & 15;
    const int gid0 = (blockIdx.x * BLOCK + tid) >> 4;
    const float4 muv = *(const float4*)(ws + 64 + g * 4);
    const float4 bev = *(const float4*)(beta + g * 4);
    float4 smu = muv, sbe = bev;
    if (g == 0) { smu.x = -smu.x; sbe.x = -sbe.x; }
    const float e0 = (g == 0) ? 1.0f : 0.0f;  // o-vector lives in lane g==0 slot .x
    const float mu0 = ws[64];
    const float beta0 = beta[0];
    const float var = ws[128] * (1.0f / (float)NROWS);
    const float divv = sqrtf(var + EPS);
    const float gscale = gamma[0] / divv;
    const float inv_dmo = 1.0f / (1.0f + mu0);
    const float inv_dob = 1.0f / (1.0f + beta0);
    #pragma unroll 4
    for (int k = 0; k < NITER; ++k) {
        const size_t r = (size_t)gid0 + (size_t)k * GPT;  // ascending = reverse of var
        const float4 xv = *(const float4*)(x + r * C + g * 4);
        // alpha = clip(-<x,mu>_L, 1+eps); x0 recovered via masked rotate-reduce
        float p = fmaf(xv.x, smu.x, fmaf(xv.y, smu.y, fmaf(xv.z, smu.z, xv.w * smu.w)));
        float x0m = (g == 0) ? xv.x : 0.0f;
        p = row16_sum(p);
        const float x0 = row16_sum(x0m);
        const float alpha = fmaxf(-p, 1.0f + ACOSH_EPS);
        const float t = fmaf(alpha, alpha, -1.0f);
        const float sq = sqrtf(t);
        const float d = __logf(alpha + sq);                 // arccosh
        const float f = d * rsqrtf(fmaxf(t, ACOSH_EPS));    // d / sqrt(clip)
        float4 v;
        v.x = f * fmaf(-alpha, muv.x, xv.x);
        v.y = f * fmaf(-alpha, muv.y, xv.y);
        v.z = f * fmaf(-alpha, muv.z, xv.z);
        v.w = f * fmaf(-alpha, muv.w, xv.w);
        // ov = -v[0] without a broadcast: v0 = f*(x0 - alpha*mu0)
        const float v0 = f * fmaf(-alpha, mu0, x0);
        const float c1 = -v0 * inv_dmo;
        v.x = fmaf(c1, muv.x + e0, v.x);
        v.y = fmaf(c1, muv.y, v.y);
        v.z = fmaf(c1, muv.z, v.z);
        v.w = fmaf(c1, muv.w, v.w);
        v.x *= gscale; v.y *= gscale; v.z *= gscale; v.w *= gscale;
        // bv = <beta, v>_L
        float bv = fmaf(v.x, sbe.x, fmaf(v.y, sbe.y, fmaf(v.z, sbe.z, v.w * sbe.w)));
        bv = row16_sum(bv);
        const float c2 = bv * inv_dob;
        v.x = fmaf(c2, bev.x + e0, v.x);
        v.y = fmaf(c2, bev.y, v.y);
        v.z = fmaf(c2, bev.z, v.z);
        v.w = fmaf(c2, bev.w, v.w);
        // vn = sqrt(clip(<v,v>_L)); out = cosh(vn)*beta + sinh(vn)/vn * v
        const float svx = (g == 0) ? -v.x : v.x;
        float nn = fmaf(v.x, svx, fmaf(v.y, v.y, fmaf(v.z, v.z, v.w * v.w)));
        nn = row16_sum(nn);
        const float vn = sqrtf(fmaxf(nn, 1e-9f));
        const float e = __expf(vn);
        const float ei = __builtin_amdgcn_rcpf(e);
        const float ch = 0.5f * (e + ei);
        const float sc = 0.5f * (e - ei) * __builtin_amdgcn_rcpf(vn);
        float4 o;
        o.x = fmaf(sc, v.x, ch * bev.x);
        o.y = fmaf(sc, v.y, ch * bev.y);
        o.z = fmaf(sc, v.z, ch * bev.z);
        o.w = fmaf(sc, v.w, ch * bev.w);
        *(float4*)(out + r * C + g * 4) = o;
    }
}

extern "C" void kernel_launch(void* const* d_in, const int* in_sizes, int n_in,
                              void* d_out, int out_size, void* d_ws, size_t ws_size,
                              hipStream_t stream) {
    const float* x = (const float*)d_in[0];
    const float* gamma = (const float*)d_in[1];
    const float* beta = (const float*)d_in[2];
    float* out = (float*)d_out;
    float* ws = (float*)d_ws;

    hipMemsetAsync(ws, 0, 129 * sizeof(float), stream);
    colsum_kernel<<<GRID, BLOCK, 0, stream>>>(x, ws);
    mu_kernel<<<1, 64, 0, stream>>>(ws);
    var_kernel<<<GRID, BLOCK, 0, stream>>>(x, ws);
    out_kernel<<<GRID, BLOCK, 0, stream>>>(x, gamma, beta, out, ws);
}